// Round 1
// baseline (209.045 us; speedup 1.0000x reference)
//
#include <hip/hip_runtime.h>
#include <hip/hip_bf16.h>
#include <math.h>

#define BB 4
#define II 2048
#define AA 2048
#define EE 256
#define HH 4

typedef __bf16 bf16_t;
typedef bf16_t bf16x8 __attribute__((ext_vector_type(8)));
typedef bf16_t bf16x4 __attribute__((ext_vector_type(4)));
typedef float  f32x4  __attribute__((ext_vector_type(4)));

static __device__ __forceinline__ f32x4 mfma16(bf16x8 a, bf16x8 b, f32x4 c) {
    return __builtin_amdgcn_mfma_f32_16x16x32_bf16(a, b, c, 0, 0, 0);
}

// massT[b][h][a] = log_cosh(key[b,a,:] . mass_w[h,:])   (f32 throughout)
__global__ __launch_bounds__(256) void mass_kernel(
    const float* __restrict__ key, const float* __restrict__ mass_w,
    float* __restrict__ massT)
{
    const int w = threadIdx.x >> 6;
    const int l = threadIdx.x & 63;
    const int row = blockIdx.x * 4 + w;            // b*AA + a
    f32x4 kv = *(const f32x4*)(key + (size_t)row * EE + l * 4);
    const int b = row >> 11, a = row & (AA - 1);
    #pragma unroll
    for (int h = 0; h < HH; ++h) {
        f32x4 mw = *(const f32x4*)(mass_w + h * EE + l * 4);
        float s = kv[0]*mw[0] + kv[1]*mw[1] + kv[2]*mw[2] + kv[3]*mw[3];
        #pragma unroll
        for (int off = 32; off >= 1; off >>= 1) s += __shfl_xor(s, off, 64);
        if (l == 0) {
            float ax = fabsf(s);
            massT[((size_t)b * HH + h) * AA + a] =
                ax + log1pf(__expf(-2.0f * ax)) - 0.693147180559945f;
        }
    }
}

// C[m][n] = sum_k A[m][k]*B[n][k]  (A,B f32 -> bf16; C bf16)
// TRANS==0: C row-major [M][256].
// TRANS==1: Vt tiled store: n = b*2048+a -> C[b][a>>6][m][a&63]  (m = e)
template<int TRANS>
__global__ __launch_bounds__(256) void proj_gemm(
    const float* __restrict__ Aop, const float* __restrict__ Bop,
    bf16_t* __restrict__ Cout)
{
    __shared__ __align__(16) bf16_t sA[64][72];
    __shared__ __align__(16) bf16_t sB[64][72];
    const int t = threadIdx.x;
    const int w = t >> 6, l = t & 63, g = l >> 4, q = l & 15;
    const int wm = w >> 1, wn = w & 1;
    const int m0 = blockIdx.x * 64, n0 = blockIdx.y * 64;
    const int r = t >> 2, s = t & 3;

    f32x4 acc[2][2] = {};

    for (int kt = 0; kt < 4; ++kt) {
        { // stage A tile (64x64 f32 -> bf16)
            const float* ga = Aop + (size_t)(m0 + r) * EE + kt * 64 + s * 16;
            float tmp[16];
            *(f32x4*)&tmp[0]  = *(const f32x4*)(ga + 0);
            *(f32x4*)&tmp[4]  = *(const f32x4*)(ga + 4);
            *(f32x4*)&tmp[8]  = *(const f32x4*)(ga + 8);
            *(f32x4*)&tmp[12] = *(const f32x4*)(ga + 12);
            bf16x8 w0, w1;
            #pragma unroll
            for (int i = 0; i < 8; ++i) { w0[i] = (bf16_t)tmp[i]; w1[i] = (bf16_t)tmp[8 + i]; }
            *(bf16x8*)&sA[r][s * 16]     = w0;
            *(bf16x8*)&sA[r][s * 16 + 8] = w1;
        }
        { // stage B tile
            const float* gb = Bop + (size_t)(n0 + r) * EE + kt * 64 + s * 16;
            float tmp[16];
            *(f32x4*)&tmp[0]  = *(const f32x4*)(gb + 0);
            *(f32x4*)&tmp[4]  = *(const f32x4*)(gb + 4);
            *(f32x4*)&tmp[8]  = *(const f32x4*)(gb + 8);
            *(f32x4*)&tmp[12] = *(const f32x4*)(gb + 12);
            bf16x8 w0, w1;
            #pragma unroll
            for (int i = 0; i < 8; ++i) { w0[i] = (bf16_t)tmp[i]; w1[i] = (bf16_t)tmp[8 + i]; }
            *(bf16x8*)&sB[r][s * 16]     = w0;
            *(bf16x8*)&sB[r][s * 16 + 8] = w1;
        }
        __syncthreads();
        #pragma unroll
        for (int ks = 0; ks < 2; ++ks) {
            bf16x8 aA[2], aB[2];
            #pragma unroll
            for (int f = 0; f < 2; ++f) {
                aA[f] = *(const bf16x8*)&sA[wm * 32 + f * 16 + q][ks * 32 + g * 8];
                aB[f] = *(const bf16x8*)&sB[wn * 32 + f * 16 + q][ks * 32 + g * 8];
            }
            #pragma unroll
            for (int fm = 0; fm < 2; ++fm)
            #pragma unroll
            for (int fn = 0; fn < 2; ++fn)
                acc[fm][fn] = mfma16(aA[fm], aB[fn], acc[fm][fn]);
        }
        __syncthreads();
    }
    #pragma unroll
    for (int fm = 0; fm < 2; ++fm)
    #pragma unroll
    for (int fn = 0; fn < 2; ++fn)
    #pragma unroll
    for (int j = 0; j < 4; ++j) {
        const int m = m0 + wm * 32 + fm * 16 + g * 4 + j;
        const int n = n0 + wn * 32 + fn * 16 + q;
        const bf16_t v = (bf16_t)acc[fm][fn][j];
        if (TRANS == 0) {
            Cout[(size_t)m * EE + n] = v;
        } else {
            const int b = n >> 11, a = n & (AA - 1);
            Cout[(size_t)b * (AA * EE) + (size_t)(a >> 6) * (EE * 64) + m * 64 + (a & 63)] = v;
        }
    }
}

// out[m][n] = sum_k Obuf[m][k] * W[n][k]   (Obuf bf16, W f32, out f32)
__global__ __launch_bounds__(256) void out_gemm(
    const bf16_t* __restrict__ Aop, const float* __restrict__ Bop,
    float* __restrict__ Cout)
{
    __shared__ __align__(16) bf16_t sA[64][72];
    __shared__ __align__(16) bf16_t sB[64][72];
    const int t = threadIdx.x;
    const int w = t >> 6, l = t & 63, g = l >> 4, q = l & 15;
    const int wm = w >> 1, wn = w & 1;
    const int m0 = blockIdx.x * 64, n0 = blockIdx.y * 64;
    const int r = t >> 2, s = t & 3;

    f32x4 acc[2][2] = {};

    for (int kt = 0; kt < 4; ++kt) {
        { // stage A (already bf16)
            const bf16_t* ga = Aop + (size_t)(m0 + r) * EE + kt * 64 + s * 16;
            *(bf16x8*)&sA[r][s * 16]     = *(const bf16x8*)(ga);
            *(bf16x8*)&sA[r][s * 16 + 8] = *(const bf16x8*)(ga + 8);
        }
        { // stage B (f32 -> bf16)
            const float* gb = Bop + (size_t)(n0 + r) * EE + kt * 64 + s * 16;
            float tmp[16];
            *(f32x4*)&tmp[0]  = *(const f32x4*)(gb + 0);
            *(f32x4*)&tmp[4]  = *(const f32x4*)(gb + 4);
            *(f32x4*)&tmp[8]  = *(const f32x4*)(gb + 8);
            *(f32x4*)&tmp[12] = *(const f32x4*)(gb + 12);
            bf16x8 w0, w1;
            #pragma unroll
            for (int i = 0; i < 8; ++i) { w0[i] = (bf16_t)tmp[i]; w1[i] = (bf16_t)tmp[8 + i]; }
            *(bf16x8*)&sB[r][s * 16]     = w0;
            *(bf16x8*)&sB[r][s * 16 + 8] = w1;
        }
        __syncthreads();
        #pragma unroll
        for (int ks = 0; ks < 2; ++ks) {
            bf16x8 aA[2], aB[2];
            #pragma unroll
            for (int f = 0; f < 2; ++f) {
                aA[f] = *(const bf16x8*)&sA[wm * 32 + f * 16 + q][ks * 32 + g * 8];
                aB[f] = *(const bf16x8*)&sB[wn * 32 + f * 16 + q][ks * 32 + g * 8];
            }
            #pragma unroll
            for (int fm = 0; fm < 2; ++fm)
            #pragma unroll
            for (int fn = 0; fn < 2; ++fn)
                acc[fm][fn] = mfma16(aA[fm], aB[fn], acc[fm][fn]);
        }
        __syncthreads();
    }
    #pragma unroll
    for (int fm = 0; fm < 2; ++fm)
    #pragma unroll
    for (int fn = 0; fn < 2; ++fn)
    #pragma unroll
    for (int j = 0; j < 4; ++j) {
        const int m = m0 + wm * 32 + fm * 16 + g * 4 + j;
        const int n = n0 + wn * 32 + fn * 16 + q;
        Cout[(size_t)m * EE + n] = acc[fm][fn][j];
    }
}

// Fused flash attention with distance-decay bias.
// Grid: 256 blocks = b(4) x i-tile(64 of 32 rows). 4 waves = 4 heads.
// S^T = mfma(K_frag, Q_frag): lane owns score column qi = lane&15.
__global__ __launch_bounds__(256) void attn_kernel(
    const bf16_t* __restrict__ Qp, const bf16_t* __restrict__ Kp,
    const bf16_t* __restrict__ Vt, const float* __restrict__ massT,
    const float* __restrict__ dist, bf16_t* __restrict__ Obuf)
{
    __shared__ __align__(16) bf16_t sK[64][264];   // 64 a x 256 e, +8 pad
    __shared__ __align__(16) bf16_t sV[256][68];   // 256 e x 64 a, +4 pad
    __shared__ __align__(16) float  sD[32][68];    // 32 i x 64 a, stride 68

    const int t = threadIdx.x;
    const int h = t >> 6, l = t & 63, g = l >> 4, q = l & 15;
    const int b  = blockIdx.x >> 6;
    const int i0 = (blockIdx.x & 63) * 32;

    // Q fragments in registers: qf[fq][ks], qi = 16*fq + q, d-slot = 32*ks + 8g + j
    bf16x8 qf[2][2];
    #pragma unroll
    for (int fq = 0; fq < 2; ++fq)
    #pragma unroll
    for (int ks = 0; ks < 2; ++ks)
        qf[fq][ks] = *(const bf16x8*)(Qp + (size_t)(b * II + i0 + fq * 16 + q) * EE
                                         + h * 64 + ks * 32 + g * 8);

    float mrun[2] = {-INFINITY, -INFINITY};
    float lrun[2] = {0.f, 0.f};
    f32x4 oacc[2][4] = {};

    const int rK = t >> 2, cK = t & 3;   // K staging: 4 thr/row
    const int rD = t >> 3, cD = t & 7;   // dist staging: 8 thr/row

    for (int a0 = 0; a0 < AA; a0 += 64) {
        { // ---- stage K / Vt / dist ----
            const bf16_t* gk = Kp + (size_t)(b * AA + a0 + rK) * EE + cK * 64;
            #pragma unroll
            for (int u = 0; u < 8; ++u)
                *(bf16x8*)&sK[rK][cK * 64 + u * 8] = *(const bf16x8*)(gk + u * 8);
            const bf16_t* gv = Vt + (size_t)b * (AA * EE) + (size_t)a0 * EE + t * 64;
            #pragma unroll
            for (int u = 0; u < 8; ++u)
                *(bf16x8*)&sV[t][u * 8] = *(const bf16x8*)(gv + u * 8);
            const float* gd = dist + ((size_t)b * II + i0 + rD) * AA + a0 + cD * 8;
            *(f32x4*)&sD[rD][cD * 8]     = *(const f32x4*)(gd);
            *(f32x4*)&sD[rD][cD * 8 + 4] = *(const f32x4*)(gd + 4);
        }
        __syncthreads();

        // mass for this head / a-tile: a = a0 + 16*fa + 4g + j
        f32x4 msr[4];
        #pragma unroll
        for (int fa = 0; fa < 4; ++fa)
            msr[fa] = *(const f32x4*)(massT + ((size_t)b * HH + h) * AA + a0 + fa * 16 + g * 4);

        // S^T[a][qi], a = 16*fa + 4g + j, qi = 16*fq + q
        f32x4 st[4][2] = {};
        #pragma unroll
        for (int fa = 0; fa < 4; ++fa)
        #pragma unroll
        for (int ks = 0; ks < 2; ++ks) {
            bf16x8 ak = *(const bf16x8*)&sK[fa * 16 + q][h * 64 + ks * 32 + g * 8];
            st[fa][0] = mfma16(ak, qf[0][ks], st[fa][0]);
            st[fa][1] = mfma16(ak, qf[1][ks], st[fa][1]);
        }
        // scale + bias, tile max
        float mloc[2] = {-INFINITY, -INFINITY};
        #pragma unroll
        for (int fq = 0; fq < 2; ++fq)
        #pragma unroll
        for (int fa = 0; fa < 4; ++fa) {
            f32x4 df = *(const f32x4*)&sD[fq * 16 + q][fa * 16 + g * 4];
            #pragma unroll
            for (int j = 0; j < 4; ++j) {
                float sv = st[fa][fq][j] * 0.125f - msr[fa][j] * df[j];
                st[fa][fq][j] = sv;
                mloc[fq] = fmaxf(mloc[fq], sv);
            }
        }
        float sc[2], mnew[2];
        #pragma unroll
        for (int fq = 0; fq < 2; ++fq) {
            float v = mloc[fq];
            v = fmaxf(v, __shfl_xor(v, 16, 64));
            v = fmaxf(v, __shfl_xor(v, 32, 64));
            mnew[fq] = fmaxf(mrun[fq], v);
            sc[fq] = __expf(mrun[fq] - mnew[fq]);
            mrun[fq] = mnew[fq];
        }
        // P = exp(S - m), row sums
        float rs[2] = {0.f, 0.f};
        #pragma unroll
        for (int fq = 0; fq < 2; ++fq)
        #pragma unroll
        for (int fa = 0; fa < 4; ++fa)
        #pragma unroll
        for (int j = 0; j < 4; ++j) {
            float e = __expf(st[fa][fq][j] - mnew[fq]);
            st[fa][fq][j] = e;
            rs[fq] += e;
        }
        #pragma unroll
        for (int fq = 0; fq < 2; ++fq) {
            float v = rs[fq];
            v += __shfl_xor(v, 16, 64);
            v += __shfl_xor(v, 32, 64);
            lrun[fq] = lrun[fq] * sc[fq] + v;
        }
        // rescale O (rows qi = 16*fm + 4g + j; scale held at lane with (lane&15)==4g+j)
        #pragma unroll
        for (int fm = 0; fm < 2; ++fm) {
            float osc[4];
            #pragma unroll
            for (int j = 0; j < 4; ++j) osc[j] = __shfl(sc[fm], g * 4 + j, 64);
            #pragma unroll
            for (int fd = 0; fd < 4; ++fd)
            #pragma unroll
            for (int j = 0; j < 4; ++j)
                oacc[fm][fd][j] *= osc[j];
        }
        // pack P into PV A-fragments: slot (g,j) -> a = 32*ka + 16*(j>>2) + 4g + (j&3)
        bf16x8 pa[2][2];
        #pragma unroll
        for (int fq = 0; fq < 2; ++fq)
        #pragma unroll
        for (int ka = 0; ka < 2; ++ka)
        #pragma unroll
        for (int j = 0; j < 8; ++j)
            pa[fq][ka][j] = (bf16_t)st[2 * ka + (j >> 2)][fq][j & 3];
        // PV: O[qi][d] += P V, B-frag from sV rows with matching slot mapping
        #pragma unroll
        for (int ka = 0; ka < 2; ++ka)
        #pragma unroll
        for (int fd = 0; fd < 4; ++fd) {
            bf16x4 v0 = *(const bf16x4*)&sV[h * 64 + fd * 16 + q][ka * 32 + g * 4];
            bf16x4 v1 = *(const bf16x4*)&sV[h * 64 + fd * 16 + q][ka * 32 + 16 + g * 4];
            bf16x8 bv;
            #pragma unroll
            for (int j = 0; j < 4; ++j) { bv[j] = v0[j]; bv[4 + j] = v1[j]; }
            #pragma unroll
            for (int fm = 0; fm < 2; ++fm)
                oacc[fm][fd] = mfma16(pa[fm][ka], bv, oacc[fm][fd]);
        }
        __syncthreads();
    }
    // normalize + store bf16 O
    #pragma unroll
    for (int fm = 0; fm < 2; ++fm) {
        float inv[4];
        #pragma unroll
        for (int j = 0; j < 4; ++j) inv[j] = 1.0f / __shfl(lrun[fm], g * 4 + j, 64);
        #pragma unroll
        for (int fd = 0; fd < 4; ++fd)
        #pragma unroll
        for (int j = 0; j < 4; ++j) {
            const int mrow = i0 + fm * 16 + g * 4 + j;
            const int ncol = h * 64 + fd * 16 + q;
            Obuf[(size_t)(b * II + mrow) * EE + ncol] = (bf16_t)(oacc[fm][fd][j] * inv[j]);
        }
    }
}

extern "C" void kernel_launch(void* const* d_in, const int* in_sizes, int n_in,
                              void* d_out, int out_size, void* d_ws, size_t ws_size,
                              hipStream_t stream)
{
    const float* query  = (const float*)d_in[0];
    const float* key    = (const float*)d_in[1];
    const float* value  = (const float*)d_in[2];
    const float* dist   = (const float*)d_in[3];
    const float* in_w   = (const float*)d_in[4];
    const float* out_w  = (const float*)d_in[5];
    const float* mass_w = (const float*)d_in[6];
    float* out = (float*)d_out;

    char* ws = (char*)d_ws;
    bf16_t* Qp    = (bf16_t*)(ws);
    bf16_t* Kp    = (bf16_t*)(ws + 1 * 4194304);
    bf16_t* Vt    = (bf16_t*)(ws + 2 * 4194304);
    bf16_t* Obuf  = (bf16_t*)(ws + 3 * 4194304);
    float*  massT = (float*) (ws + 4 * 4194304);

    dim3 blk(256);
    proj_gemm<0><<<dim3(128, 4), blk, 0, stream>>>(query, in_w,           Qp);
    proj_gemm<0><<<dim3(128, 4), blk, 0, stream>>>(key,   in_w + 65536,   Kp);
    proj_gemm<1><<<dim3(4, 128), blk, 0, stream>>>(in_w + 131072, value,  Vt);
    mass_kernel<<<dim3(2048), blk, 0, stream>>>(key, mass_w, massT);
    attn_kernel<<<dim3(256), blk, 0, stream>>>(Qp, Kp, Vt, massT, dist, Obuf);
    out_gemm<<<dim3(128, 4), blk, 0, stream>>>(Obuf, out_w, out);
}

// Round 2
// 98.971 us; speedup vs baseline: 2.1122x; 2.1122x over previous
//
#include <hip/hip_runtime.h>
#include <hip/hip_bf16.h>
#include <math.h>

#define BB 4
#define II 2048
#define AA 2048
#define EE 256
#define HH 4

typedef __bf16 bf16_t;
typedef bf16_t bf16x8 __attribute__((ext_vector_type(8)));
typedef bf16_t bf16x4 __attribute__((ext_vector_type(4)));
typedef float  f32x4  __attribute__((ext_vector_type(4)));

static __device__ __forceinline__ f32x4 mfma16(bf16x8 a, bf16x8 b, f32x4 c) {
    return __builtin_amdgcn_mfma_f32_16x16x32_bf16(a, b, c, 0, 0, 0);
}

// massT[b][h][a] = log_cosh(key[b,a,:] . mass_w[h,:])   (f32 throughout)
__global__ __launch_bounds__(256) void mass_kernel(
    const float* __restrict__ key, const float* __restrict__ mass_w,
    float* __restrict__ massT)
{
    const int w = threadIdx.x >> 6;
    const int l = threadIdx.x & 63;
    const int row = blockIdx.x * 4 + w;            // b*AA + a
    f32x4 kv = *(const f32x4*)(key + (size_t)row * EE + l * 4);
    const int b = row >> 11, a = row & (AA - 1);
    #pragma unroll
    for (int h = 0; h < HH; ++h) {
        f32x4 mw = *(const f32x4*)(mass_w + h * EE + l * 4);
        float s = kv[0]*mw[0] + kv[1]*mw[1] + kv[2]*mw[2] + kv[3]*mw[3];
        #pragma unroll
        for (int off = 32; off >= 1; off >>= 1) s += __shfl_xor(s, off, 64);
        if (l == 0) {
            float ax = fabsf(s);
            massT[((size_t)b * HH + h) * AA + a] =
                ax + log1pf(__expf(-2.0f * ax)) - 0.693147180559945f;
        }
    }
}

// C[m][n] = sum_k A[m][k]*B[n][k]  (A,B f32 -> bf16; C bf16)
// TRANS==0: C row-major [M][256].
// TRANS==1: Vt tiled store: n = b*2048+a -> C[b][a>>6][m][a&63]  (m = e)
template<int TRANS>
__global__ __launch_bounds__(256) void proj_gemm(
    const float* __restrict__ Aop, const float* __restrict__ Bop,
    bf16_t* __restrict__ Cout)
{
    __shared__ __align__(16) bf16_t sA[64][72];
    __shared__ __align__(16) bf16_t sB[64][72];
    const int t = threadIdx.x;
    const int w = t >> 6, l = t & 63, g = l >> 4, q = l & 15;
    const int wm = w >> 1, wn = w & 1;
    const int m0 = blockIdx.x * 64, n0 = blockIdx.y * 64;
    const int r = t >> 2, s = t & 3;

    f32x4 acc[2][2] = {};

    for (int kt = 0; kt < 4; ++kt) {
        {
            const float* ga = Aop + (size_t)(m0 + r) * EE + kt * 64 + s * 16;
            float tmp[16];
            *(f32x4*)&tmp[0]  = *(const f32x4*)(ga + 0);
            *(f32x4*)&tmp[4]  = *(const f32x4*)(ga + 4);
            *(f32x4*)&tmp[8]  = *(const f32x4*)(ga + 8);
            *(f32x4*)&tmp[12] = *(const f32x4*)(ga + 12);
            bf16x8 w0, w1;
            #pragma unroll
            for (int i = 0; i < 8; ++i) { w0[i] = (bf16_t)tmp[i]; w1[i] = (bf16_t)tmp[8 + i]; }
            *(bf16x8*)&sA[r][s * 16]     = w0;
            *(bf16x8*)&sA[r][s * 16 + 8] = w1;
        }
        {
            const float* gb = Bop + (size_t)(n0 + r) * EE + kt * 64 + s * 16;
            float tmp[16];
            *(f32x4*)&tmp[0]  = *(const f32x4*)(gb + 0);
            *(f32x4*)&tmp[4]  = *(const f32x4*)(gb + 4);
            *(f32x4*)&tmp[8]  = *(const f32x4*)(gb + 8);
            *(f32x4*)&tmp[12] = *(const f32x4*)(gb + 12);
            bf16x8 w0, w1;
            #pragma unroll
            for (int i = 0; i < 8; ++i) { w0[i] = (bf16_t)tmp[i]; w1[i] = (bf16_t)tmp[8 + i]; }
            *(bf16x8*)&sB[r][s * 16]     = w0;
            *(bf16x8*)&sB[r][s * 16 + 8] = w1;
        }
        __syncthreads();
        #pragma unroll
        for (int ks = 0; ks < 2; ++ks) {
            bf16x8 aA[2], aB[2];
            #pragma unroll
            for (int f = 0; f < 2; ++f) {
                aA[f] = *(const bf16x8*)&sA[wm * 32 + f * 16 + q][ks * 32 + g * 8];
                aB[f] = *(const bf16x8*)&sB[wn * 32 + f * 16 + q][ks * 32 + g * 8];
            }
            #pragma unroll
            for (int fm = 0; fm < 2; ++fm)
            #pragma unroll
            for (int fn = 0; fn < 2; ++fn)
                acc[fm][fn] = mfma16(aA[fm], aB[fn], acc[fm][fn]);
        }
        __syncthreads();
    }
    #pragma unroll
    for (int fm = 0; fm < 2; ++fm)
    #pragma unroll
    for (int fn = 0; fn < 2; ++fn)
    #pragma unroll
    for (int j = 0; j < 4; ++j) {
        const int m = m0 + wm * 32 + fm * 16 + g * 4 + j;
        const int n = n0 + wn * 32 + fn * 16 + q;
        const bf16_t v = (bf16_t)acc[fm][fn][j];
        if (TRANS == 0) {
            Cout[(size_t)m * EE + n] = v;
        } else {
            const int b = n >> 11, a = n & (AA - 1);
            Cout[(size_t)b * (AA * EE) + (size_t)(a >> 6) * (EE * 64) + m * 64 + (a & 63)] = v;
        }
    }
}

// out[m][n] = sum_k Obuf[m][k] * W[n][k]   (Obuf bf16, W f32, out f32)
__global__ __launch_bounds__(256) void out_gemm(
    const bf16_t* __restrict__ Aop, const float* __restrict__ Bop,
    float* __restrict__ Cout)
{
    __shared__ __align__(16) bf16_t sA[64][72];
    __shared__ __align__(16) bf16_t sB[64][72];
    const int t = threadIdx.x;
    const int w = t >> 6, l = t & 63, g = l >> 4, q = l & 15;
    const int wm = w >> 1, wn = w & 1;
    const int m0 = blockIdx.x * 64, n0 = blockIdx.y * 64;
    const int r = t >> 2, s = t & 3;

    f32x4 acc[2][2] = {};

    for (int kt = 0; kt < 4; ++kt) {
        {
            const bf16_t* ga = Aop + (size_t)(m0 + r) * EE + kt * 64 + s * 16;
            *(bf16x8*)&sA[r][s * 16]     = *(const bf16x8*)(ga);
            *(bf16x8*)&sA[r][s * 16 + 8] = *(const bf16x8*)(ga + 8);
        }
        {
            const float* gb = Bop + (size_t)(n0 + r) * EE + kt * 64 + s * 16;
            float tmp[16];
            *(f32x4*)&tmp[0]  = *(const f32x4*)(gb + 0);
            *(f32x4*)&tmp[4]  = *(const f32x4*)(gb + 4);
            *(f32x4*)&tmp[8]  = *(const f32x4*)(gb + 8);
            *(f32x4*)&tmp[12] = *(const f32x4*)(gb + 12);
            bf16x8 w0, w1;
            #pragma unroll
            for (int i = 0; i < 8; ++i) { w0[i] = (bf16_t)tmp[i]; w1[i] = (bf16_t)tmp[8 + i]; }
            *(bf16x8*)&sB[r][s * 16]     = w0;
            *(bf16x8*)&sB[r][s * 16 + 8] = w1;
        }
        __syncthreads();
        #pragma unroll
        for (int ks = 0; ks < 2; ++ks) {
            bf16x8 aA[2], aB[2];
            #pragma unroll
            for (int f = 0; f < 2; ++f) {
                aA[f] = *(const bf16x8*)&sA[wm * 32 + f * 16 + q][ks * 32 + g * 8];
                aB[f] = *(const bf16x8*)&sB[wn * 32 + f * 16 + q][ks * 32 + g * 8];
            }
            #pragma unroll
            for (int fm = 0; fm < 2; ++fm)
            #pragma unroll
            for (int fn = 0; fn < 2; ++fn)
                acc[fm][fn] = mfma16(aA[fm], aB[fn], acc[fm][fn]);
        }
        __syncthreads();
    }
    #pragma unroll
    for (int fm = 0; fm < 2; ++fm)
    #pragma unroll
    for (int fn = 0; fn < 2; ++fn)
    #pragma unroll
    for (int j = 0; j < 4; ++j) {
        const int m = m0 + wm * 32 + fm * 16 + g * 4 + j;
        const int n = n0 + wn * 32 + fn * 16 + q;
        Cout[(size_t)m * EE + n] = acc[fm][fn][j];
    }
}

// Fused flash attention, per-head blocks.
// Grid: (32 i-tiles, 4 heads, 4 batches). 4 waves; wave w owns i-rows [i0+16w, i0+16w+16).
// Double-buffered reg-staged LDS; XOR chunk swizzle on K/V; pad on dist.
__global__ __launch_bounds__(256, 2) void attn_kernel(
    const bf16_t* __restrict__ Qp, const bf16_t* __restrict__ Kp,
    const bf16_t* __restrict__ Vt, const float* __restrict__ massT,
    const float* __restrict__ dist, bf16_t* __restrict__ Obuf)
{
    __shared__ __align__(16) bf16_t sK[2][64 * 64];   // [a][d]  chunk^=(a&7)
    __shared__ __align__(16) bf16_t sV[2][64 * 64];   // [d][a]  chunk^=(d&7)
    __shared__ __align__(16) float  sD[2][64 * 68];   // [i][a]  +4 pad
    __shared__ __align__(16) float  sM[AA];           // mass row for (b,h)

    const int t = threadIdx.x;
    const int w = t >> 6, l = t & 63, g = l >> 4, q = l & 15;
    const int h = blockIdx.y, b = blockIdx.z;
    const int i0 = blockIdx.x * 64;

    { // preload full mass row (8 KB) once
        const float* gm = massT + ((size_t)b * HH + h) * AA + t * 8;
        *(f32x4*)&sM[t * 8]     = *(const f32x4*)(gm);
        *(f32x4*)&sM[t * 8 + 4] = *(const f32x4*)(gm + 4);
    }

    // Q fragments: rows i0+16w+q, d = h*64 + ks*32 + g*8 + j
    bf16x8 qf[2];
    #pragma unroll
    for (int ks = 0; ks < 2; ++ks)
        qf[ks] = *(const bf16x8*)(Qp + (size_t)(b * II + i0 + w * 16 + q) * EE
                                     + h * 64 + ks * 32 + g * 8);

    // staging assignment: thread t -> row sr (0..63), 16B-chunk pair sc, sc+1
    const int sr = t >> 2;
    const int sc = (t & 3) * 2;
    const int z0 = ((sc)     ^ (sr & 7)) * 8;   // swizzled bf16 elem offset
    const int z1 = ((sc + 1) ^ (sr & 7)) * 8;

    const bf16_t* gK = Kp + ((size_t)b * AA + sr) * EE + h * 64 + sc * 8;
    const bf16_t* gV = Vt + (size_t)b * (AA * EE) + (size_t)(h * 64 + sr) * 64 + sc * 8;
    const float*  gD = dist + ((size_t)b * II + i0 + sr) * AA + (t & 3) * 16;

    bf16x8 rk0, rk1, rv0, rv1;
    f32x4 rd0, rd1, rd2, rd3;

    auto load_regs = [&](int a0) {
        const bf16_t* pk = gK + (size_t)a0 * EE;
        rk0 = *(const bf16x8*)(pk);
        rk1 = *(const bf16x8*)(pk + 8);
        const bf16_t* pv = gV + (size_t)(a0 >> 6) * (EE * 64);
        rv0 = *(const bf16x8*)(pv);
        rv1 = *(const bf16x8*)(pv + 8);
        const float* pd = gD + a0;
        rd0 = *(const f32x4*)(pd);
        rd1 = *(const f32x4*)(pd + 4);
        rd2 = *(const f32x4*)(pd + 8);
        rd3 = *(const f32x4*)(pd + 12);
    };
    auto write_stage = [&](int buf) {
        *(bf16x8*)&sK[buf][sr * 64 + z0] = rk0;
        *(bf16x8*)&sK[buf][sr * 64 + z1] = rk1;
        *(bf16x8*)&sV[buf][sr * 64 + z0] = rv0;
        *(bf16x8*)&sV[buf][sr * 64 + z1] = rv1;
        float* pd = &sD[buf][sr * 68 + (t & 3) * 16];
        *(f32x4*)(pd)      = rd0;
        *(f32x4*)(pd + 4)  = rd1;
        *(f32x4*)(pd + 8)  = rd2;
        *(f32x4*)(pd + 12) = rd3;
    };

    float mrun = -INFINITY, lrun = 0.f;
    f32x4 oacc[4] = {};

    load_regs(0);
    write_stage(0);
    __syncthreads();

    for (int tt = 0; tt < 32; ++tt) {
        const int buf = tt & 1;
        const int a0 = tt * 64;
        if (tt < 31) load_regs(a0 + 64);     // issue early; latency hides under compute

        // ---- QK^T:  S^T[a = fa*16+4g+j][i = q] ----
        f32x4 st[4] = {};
        __builtin_amdgcn_s_setprio(1);
        #pragma unroll
        for (int fa = 0; fa < 4; ++fa) {
            const int row = fa * 16 + q;
            #pragma unroll
            for (int ks = 0; ks < 2; ++ks) {
                bf16x8 ak = *(const bf16x8*)&sK[buf][row * 64 + (((ks * 4 + g) ^ (row & 7)) * 8)];
                st[fa] = mfma16(ak, qf[ks], st[fa]);
            }
        }
        __builtin_amdgcn_s_setprio(0);

        // ---- bias + row max ----
        float mloc = -INFINITY;
        const int drow = w * 16 + q;
        #pragma unroll
        for (int fa = 0; fa < 4; ++fa) {
            f32x4 df = *(const f32x4*)&sD[buf][drow * 68 + fa * 16 + g * 4];
            f32x4 ms = *(const f32x4*)&sM[a0 + fa * 16 + g * 4];
            #pragma unroll
            for (int j = 0; j < 4; ++j) {
                float sv = st[fa][j] * 0.125f - ms[j] * df[j];
                st[fa][j] = sv;
                mloc = fmaxf(mloc, sv);
            }
        }
        mloc = fmaxf(mloc, __shfl_xor(mloc, 16, 64));
        mloc = fmaxf(mloc, __shfl_xor(mloc, 32, 64));

        const bool skip = __all(mloc <= mrun);   // defer-max (exact, THR=0)
        float mnew, sc;
        if (skip) { mnew = mrun; sc = 1.f; }
        else { mnew = fmaxf(mrun, mloc); sc = __expf(mrun - mnew); mrun = mnew; }

        float rs = 0.f;
        #pragma unroll
        for (int fa = 0; fa < 4; ++fa)
        #pragma unroll
        for (int j = 0; j < 4; ++j) {
            float e = __expf(st[fa][j] - mnew);
            st[fa][j] = e;
            rs += e;
        }
        rs += __shfl_xor(rs, 16, 64);
        rs += __shfl_xor(rs, 32, 64);
        lrun = lrun * sc + rs;

        if (!skip) {
            float osc[4];
            #pragma unroll
            for (int j = 0; j < 4; ++j) osc[j] = __shfl(sc, g * 4 + j, 64);
            #pragma unroll
            for (int fd = 0; fd < 4; ++fd)
            #pragma unroll
            for (int j = 0; j < 4; ++j) oacc[fd][j] *= osc[j];
        }

        // ---- pack P, PV ----  slot (g,j): a = ka*32 + 16*(j>>2) + 4g + (j&3)
        bf16x8 pa[2];
        #pragma unroll
        for (int ka = 0; ka < 2; ++ka)
        #pragma unroll
        for (int j = 0; j < 8; ++j)
            pa[ka][j] = (bf16_t)st[2 * ka + (j >> 2)][j & 3];

        __builtin_amdgcn_s_setprio(1);
        #pragma unroll
        for (int ka = 0; ka < 2; ++ka)
        #pragma unroll
        for (int fd = 0; fd < 4; ++fd) {
            const int row = fd * 16 + q;
            const int base = row * 64 + (g & 1) * 4;
            bf16x4 v0 = *(const bf16x4*)&sV[buf][base + (((ka * 4 +     (g >> 1)) ^ (row & 7)) * 8)];
            bf16x4 v1 = *(const bf16x4*)&sV[buf][base + (((ka * 4 + 2 + (g >> 1)) ^ (row & 7)) * 8)];
            bf16x8 bv;
            #pragma unroll
            for (int j = 0; j < 4; ++j) { bv[j] = v0[j]; bv[4 + j] = v1[j]; }
            oacc[fd] = mfma16(pa[ka], bv, oacc[fd]);
        }
        __builtin_amdgcn_s_setprio(0);

        if (tt < 31) write_stage(buf ^ 1);   // waits vmcnt internally
        __syncthreads();
    }

    // ---- normalize + store ----
    float inv[4];
    #pragma unroll
    for (int j = 0; j < 4; ++j) inv[j] = 1.0f / __shfl(lrun, g * 4 + j, 64);
    #pragma unroll
    for (int fd = 0; fd < 4; ++fd)
    #pragma unroll
    for (int j = 0; j < 4; ++j) {
        const int mrow = i0 + w * 16 + g * 4 + j;
        const int ncol = h * 64 + fd * 16 + q;
        Obuf[(size_t)(b * II + mrow) * EE + ncol] = (bf16_t)(oacc[fd][j] * inv[j]);
    }
}

extern "C" void kernel_launch(void* const* d_in, const int* in_sizes, int n_in,
                              void* d_out, int out_size, void* d_ws, size_t ws_size,
                              hipStream_t stream)
{
    const float* query  = (const float*)d_in[0];
    const float* key    = (const float*)d_in[1];
    const float* value  = (const float*)d_in[2];
    const float* dist   = (const float*)d_in[3];
    const float* in_w   = (const float*)d_in[4];
    const float* out_w  = (const float*)d_in[5];
    const float* mass_w = (const float*)d_in[6];
    float* out = (float*)d_out;

    char* ws = (char*)d_ws;
    bf16_t* Qp    = (bf16_t*)(ws);
    bf16_t* Kp    = (bf16_t*)(ws + 1 * 4194304);
    bf16_t* Vt    = (bf16_t*)(ws + 2 * 4194304);
    bf16_t* Obuf  = (bf16_t*)(ws + 3 * 4194304);
    float*  massT = (float*) (ws + 4 * 4194304);

    dim3 blk(256);
    proj_gemm<0><<<dim3(128, 4), blk, 0, stream>>>(query, in_w,           Qp);
    proj_gemm<0><<<dim3(128, 4), blk, 0, stream>>>(key,   in_w + 65536,   Kp);
    proj_gemm<1><<<dim3(4, 128), blk, 0, stream>>>(in_w + 131072, value,  Vt);
    mass_kernel<<<dim3(2048), blk, 0, stream>>>(key, mass_w, massT);
    attn_kernel<<<dim3(32, 4, 4), blk, 0, stream>>>(Qp, Kp, Vt, massT, dist, Obuf);
    out_gemm<<<dim3(128, 4), blk, 0, stream>>>(Obuf, out_w, out);
}

// Round 3
// 91.959 us; speedup vs baseline: 2.2732x; 1.0763x over previous
//
#include <hip/hip_runtime.h>
#include <hip/hip_bf16.h>
#include <math.h>

#define BB 4
#define II 2048
#define AA 2048
#define EE 256
#define HH 4

#define LOG2E 1.4426950408889634f
#define SCL   (0.125f * LOG2E)

typedef __bf16 bf16_t;
typedef bf16_t bf16x8 __attribute__((ext_vector_type(8)));
typedef bf16_t bf16x4 __attribute__((ext_vector_type(4)));
typedef float  f32x4  __attribute__((ext_vector_type(4)));

static __device__ __forceinline__ f32x4 mfma16(bf16x8 a, bf16x8 b, f32x4 c) {
    return __builtin_amdgcn_mfma_f32_16x16x32_bf16(a, b, c, 0, 0, 0);
}

static __device__ __forceinline__ void glds16(const bf16_t* g, const bf16_t* l) {
    __builtin_amdgcn_global_load_lds(
        (const __attribute__((address_space(1))) void*)g,
        (__attribute__((address_space(3))) void*)l, 16, 0, 0);
}

// ---------------- fused pre-pass: Q/K/V projections + mass ----------------
// C[m][n] = sum_k A[m][k]*B[n][k]; TRANS=1 stores Vt tiled layout.
static __device__ __forceinline__ void proj_body(
    const float* __restrict__ Aop, const float* __restrict__ Bop,
    bf16_t* __restrict__ Cout, int m0, int n0, int TRANS,
    bf16_t (*sA)[72], bf16_t (*sB)[72])
{
    const int t = threadIdx.x;
    const int w = t >> 6, l = t & 63, g = l >> 4, q = l & 15;
    const int wm = w >> 1, wn = w & 1;
    const int r = t >> 2, s = t & 3;

    f32x4 acc[2][2] = {};

    for (int kt = 0; kt < 4; ++kt) {
        {
            const float* ga = Aop + (size_t)(m0 + r) * EE + kt * 64 + s * 16;
            float tmp[16];
            *(f32x4*)&tmp[0]  = *(const f32x4*)(ga + 0);
            *(f32x4*)&tmp[4]  = *(const f32x4*)(ga + 4);
            *(f32x4*)&tmp[8]  = *(const f32x4*)(ga + 8);
            *(f32x4*)&tmp[12] = *(const f32x4*)(ga + 12);
            bf16x8 w0, w1;
            #pragma unroll
            for (int i = 0; i < 8; ++i) { w0[i] = (bf16_t)tmp[i]; w1[i] = (bf16_t)tmp[8 + i]; }
            *(bf16x8*)&sA[r][s * 16]     = w0;
            *(bf16x8*)&sA[r][s * 16 + 8] = w1;
        }
        {
            const float* gb = Bop + (size_t)(n0 + r) * EE + kt * 64 + s * 16;
            float tmp[16];
            *(f32x4*)&tmp[0]  = *(const f32x4*)(gb + 0);
            *(f32x4*)&tmp[4]  = *(const f32x4*)(gb + 4);
            *(f32x4*)&tmp[8]  = *(const f32x4*)(gb + 8);
            *(f32x4*)&tmp[12] = *(const f32x4*)(gb + 12);
            bf16x8 w0, w1;
            #pragma unroll
            for (int i = 0; i < 8; ++i) { w0[i] = (bf16_t)tmp[i]; w1[i] = (bf16_t)tmp[8 + i]; }
            *(bf16x8*)&sB[r][s * 16]     = w0;
            *(bf16x8*)&sB[r][s * 16 + 8] = w1;
        }
        __syncthreads();
        #pragma unroll
        for (int ks = 0; ks < 2; ++ks) {
            bf16x8 aA[2], aB[2];
            #pragma unroll
            for (int f = 0; f < 2; ++f) {
                aA[f] = *(const bf16x8*)&sA[wm * 32 + f * 16 + q][ks * 32 + g * 8];
                aB[f] = *(const bf16x8*)&sB[wn * 32 + f * 16 + q][ks * 32 + g * 8];
            }
            #pragma unroll
            for (int fm = 0; fm < 2; ++fm)
            #pragma unroll
            for (int fn = 0; fn < 2; ++fn)
                acc[fm][fn] = mfma16(aA[fm], aB[fn], acc[fm][fn]);
        }
        __syncthreads();
    }
    #pragma unroll
    for (int fm = 0; fm < 2; ++fm)
    #pragma unroll
    for (int fn = 0; fn < 2; ++fn)
    #pragma unroll
    for (int j = 0; j < 4; ++j) {
        const int m = m0 + wm * 32 + fm * 16 + g * 4 + j;
        const int n = n0 + wn * 32 + fn * 16 + q;
        const bf16_t v = (bf16_t)acc[fm][fn][j];
        if (TRANS == 0) {
            Cout[(size_t)m * EE + n] = v;
        } else {
            const int bb = n >> 11, a = n & (AA - 1);
            Cout[(size_t)bb * (AA * EE) + (size_t)(a >> 6) * (EE * 64) + m * 64 + (a & 63)] = v;
        }
    }
}

__global__ __launch_bounds__(256) void fused_pre(
    const float* __restrict__ query, const float* __restrict__ key,
    const float* __restrict__ value, const float* __restrict__ in_w,
    const float* __restrict__ mass_w,
    bf16_t* __restrict__ Qp, bf16_t* __restrict__ Kp, bf16_t* __restrict__ Vt,
    float* __restrict__ massT)
{
    __shared__ __align__(16) bf16_t sA[64][72];
    __shared__ __align__(16) bf16_t sB[64][72];
    const int z = blockIdx.z;
    if (z == 0) {
        proj_body(query, in_w, Qp, blockIdx.x * 64, blockIdx.y * 64, 0, sA, sB);
    } else if (z == 1) {
        proj_body(key, in_w + 65536, Kp, blockIdx.x * 64, blockIdx.y * 64, 0, sA, sB);
    } else if (z == 2) {
        proj_body(in_w + 131072, value, Vt, blockIdx.y * 64, blockIdx.x * 64, 1, sA, sB);
    } else {
        // mass: massT[b][h][a] = log_cosh(key[b,a,:].mass_w[h,:]) * LOG2E
        const int w = threadIdx.x >> 6, l = threadIdx.x & 63;
        const int p = blockIdx.y * 128 + blockIdx.x;      // 0..511
        const int row0 = p * 16 + w * 4;
        #pragma unroll
        for (int rr = 0; rr < 4; ++rr) {
            const int row = row0 + rr;                     // b*AA + a
            f32x4 kv = *(const f32x4*)(key + (size_t)row * EE + l * 4);
            const int bb = row >> 11, a = row & (AA - 1);
            #pragma unroll
            for (int hh = 0; hh < HH; ++hh) {
                f32x4 mw = *(const f32x4*)(mass_w + hh * EE + l * 4);
                float sdot = kv[0]*mw[0] + kv[1]*mw[1] + kv[2]*mw[2] + kv[3]*mw[3];
                #pragma unroll
                for (int off = 32; off >= 1; off >>= 1) sdot += __shfl_xor(sdot, off, 64);
                if (l == 0) {
                    float ax = fabsf(sdot);
                    massT[((size_t)bb * HH + hh) * AA + a] =
                        (ax + log1pf(__expf(-2.0f * ax)) - 0.693147180559945f) * LOG2E;
                }
            }
        }
    }
}

// out[m][n] = sum_k Obuf[m][k] * W[n][k]
__global__ __launch_bounds__(256) void out_gemm(
    const bf16_t* __restrict__ Aop, const float* __restrict__ Bop,
    float* __restrict__ Cout)
{
    __shared__ __align__(16) bf16_t sA[64][72];
    __shared__ __align__(16) bf16_t sB[64][72];
    const int t = threadIdx.x;
    const int w = t >> 6, l = t & 63, g = l >> 4, q = l & 15;
    const int wm = w >> 1, wn = w & 1;
    const int m0 = blockIdx.x * 64, n0 = blockIdx.y * 64;
    const int r = t >> 2, s = t & 3;

    f32x4 acc[2][2] = {};

    for (int kt = 0; kt < 4; ++kt) {
        {
            const bf16_t* ga = Aop + (size_t)(m0 + r) * EE + kt * 64 + s * 16;
            *(bf16x8*)&sA[r][s * 16]     = *(const bf16x8*)(ga);
            *(bf16x8*)&sA[r][s * 16 + 8] = *(const bf16x8*)(ga + 8);
        }
        {
            const float* gb = Bop + (size_t)(n0 + r) * EE + kt * 64 + s * 16;
            float tmp[16];
            *(f32x4*)&tmp[0]  = *(const f32x4*)(gb + 0);
            *(f32x4*)&tmp[4]  = *(const f32x4*)(gb + 4);
            *(f32x4*)&tmp[8]  = *(const f32x4*)(gb + 8);
            *(f32x4*)&tmp[12] = *(const f32x4*)(gb + 12);
            bf16x8 w0, w1;
            #pragma unroll
            for (int i = 0; i < 8; ++i) { w0[i] = (bf16_t)tmp[i]; w1[i] = (bf16_t)tmp[8 + i]; }
            *(bf16x8*)&sB[r][s * 16]     = w0;
            *(bf16x8*)&sB[r][s * 16 + 8] = w1;
        }
        __syncthreads();
        #pragma unroll
        for (int ks = 0; ks < 2; ++ks) {
            bf16x8 aA[2], aB[2];
            #pragma unroll
            for (int f = 0; f < 2; ++f) {
                aA[f] = *(const bf16x8*)&sA[wm * 32 + f * 16 + q][ks * 32 + g * 8];
                aB[f] = *(const bf16x8*)&sB[wn * 32 + f * 16 + q][ks * 32 + g * 8];
            }
            #pragma unroll
            for (int fm = 0; fm < 2; ++fm)
            #pragma unroll
            for (int fn = 0; fn < 2; ++fn)
                acc[fm][fn] = mfma16(aA[fm], aB[fn], acc[fm][fn]);
        }
        __syncthreads();
    }
    #pragma unroll
    for (int fm = 0; fm < 2; ++fm)
    #pragma unroll
    for (int fn = 0; fn < 2; ++fn)
    #pragma unroll
    for (int j = 0; j < 4; ++j) {
        const int m = m0 + wm * 32 + fm * 16 + g * 4 + j;
        const int n = n0 + wn * 32 + fn * 16 + q;
        Cout[(size_t)m * EE + n] = acc[fm][fn][j];
    }
}

// ---------------- fused flash attention ----------------
// Grid (32,4,4) blocks of 512 threads = 8 waves.
// Wave = (parity s = wv>>2, row-group rg = wv&3). Parity s handles a-tiles 2k+s,
// each parity has its own double-buffered K/V LDS quad. One barrier per tile.
// K/V staged by global_load_lds (linear LDS dest, XOR-swizzled global source);
// dist read global->reg in compute layout, prefetched one tile ahead.
__global__ __launch_bounds__(512, 4) void attn_kernel(
    const bf16_t* __restrict__ Qp, const bf16_t* __restrict__ Kp,
    const bf16_t* __restrict__ Vt, const float* __restrict__ massT,
    const float* __restrict__ dist, bf16_t* __restrict__ Obuf)
{
    __shared__ __align__(16) bf16_t sK[2][2][4096];   // [parity][buf][64a x 64d] chunk^=(row&7)
    __shared__ __align__(16) bf16_t sV[2][2][4096];   // [parity][buf][64d x 64a] chunk^=(row&7)
    __shared__ __align__(16) float  sM[2048];         // mass row (log2 domain)

    const int t = threadIdx.x;
    const int wv = t >> 6, l = t & 63, g = l >> 4, q = l & 15;
    const int s = wv >> 2, rg = wv & 3;
    const int h = blockIdx.y, b = blockIdx.z;
    const int i0 = blockIdx.x * 64;

    *(f32x4*)&sM[t * 4] = *(const f32x4*)(massT + ((size_t)b * HH + h) * AA + t * 4);

    // Q fragments: rows i0+rg*16+q, d = h*64 + ks*32 + g*8 + j
    bf16x8 qf[2];
    #pragma unroll
    for (int ks = 0; ks < 2; ++ks)
        qf[ks] = *(const bf16x8*)(Qp + (size_t)(b * II + i0 + rg * 16 + q) * EE
                                     + h * 64 + ks * 32 + g * 8);

    // glds geometry: wave writes 2x1KB chunks; lane l covers (row, 16B-chunk c)
    const int u0 = rg * 2;
    const int drow0 = u0 * 8 + (l >> 3);
    const int cc = l & 7;

    auto stage = [&](int a0, int kb) {
        #pragma unroll
        for (int u = 0; u < 2; ++u) {
            const int dr = drow0 + u * 8;
            const int cs = cc ^ (dr & 7);           // pre-swizzled source chunk
            glds16(Kp + ((size_t)b * AA + a0 + dr) * EE + h * 64 + cs * 8,
                   &sK[s][kb][(u0 + u) * 512]);
            glds16(Vt + (size_t)b * (AA * EE) + (size_t)(a0 >> 6) * (EE * 64)
                      + (size_t)(h * 64 + dr) * 64 + cs * 8,
                   &sV[s][kb][(u0 + u) * 512]);
        }
    };

    f32x4 rd[4];
    auto load_dist = [&](int a0) {
        const float* gd = dist + ((size_t)b * II + i0 + rg * 16 + q) * AA + a0 + g * 4;
        #pragma unroll
        for (int fa = 0; fa < 4; ++fa) rd[fa] = *(const f32x4*)(gd + fa * 16);
    };

    stage(s * 64, 0);
    load_dist(s * 64);
    __syncthreads();

    float mrun = -INFINITY, lrun = 0.f;
    f32x4 oacc[4] = {};

    for (int k = 0; k < 16; ++k) {
        const int kb = k & 1;
        const int a0 = (2 * k + s) * 64;
        if (k < 15) stage(a0 + 128, kb ^ 1);   // async into other buffer

        // ---- QK^T: S^T[a = fa*16+4g+j][i = q] ----
        f32x4 st[4] = {};
        __builtin_amdgcn_s_setprio(1);
        #pragma unroll
        for (int fa = 0; fa < 4; ++fa) {
            const int row = fa * 16 + q;
            #pragma unroll
            for (int ks = 0; ks < 2; ++ks) {
                bf16x8 ak = *(const bf16x8*)&sK[s][kb][row * 64 + (((ks * 4 + g) ^ (row & 7)) * 8)];
                st[fa] = mfma16(ak, qf[ks], st[fa]);
            }
        }
        __builtin_amdgcn_s_setprio(0);

        // ---- bias (log2 domain) + row max ----
        float mloc = -INFINITY;
        #pragma unroll
        for (int fa = 0; fa < 4; ++fa) {
            f32x4 ms = *(const f32x4*)&sM[a0 + fa * 16 + g * 4];
            #pragma unroll
            for (int j = 0; j < 4; ++j) {
                float sv = st[fa][j] * SCL - ms[j] * rd[fa][j];
                st[fa][j] = sv;
                mloc = fmaxf(mloc, sv);
            }
        }
        if (k < 15) load_dist(a0 + 128);       // prefetch next tile's dist

        mloc = fmaxf(mloc, __shfl_xor(mloc, 16, 64));
        mloc = fmaxf(mloc, __shfl_xor(mloc, 32, 64));
        const bool skip = __all(mloc <= mrun); // defer-max (exact)
        float mnew, sc;
        if (skip) { mnew = mrun; sc = 1.f; }
        else { mnew = fmaxf(mrun, mloc); sc = exp2f(mrun - mnew); mrun = mnew; }

        float rs = 0.f;
        #pragma unroll
        for (int fa = 0; fa < 4; ++fa)
        #pragma unroll
        for (int j = 0; j < 4; ++j) {
            float e = exp2f(st[fa][j] - mnew);
            st[fa][j] = e;
            rs += e;
        }
        rs += __shfl_xor(rs, 16, 64);
        rs += __shfl_xor(rs, 32, 64);
        lrun = lrun * sc + rs;

        if (!skip) {
            float osc[4];
            #pragma unroll
            for (int j = 0; j < 4; ++j) osc[j] = __shfl(sc, g * 4 + j, 64);
            #pragma unroll
            for (int fd = 0; fd < 4; ++fd)
            #pragma unroll
            for (int j = 0; j < 4; ++j) oacc[fd][j] *= osc[j];
        }

        // ---- pack P: slot (g,j) -> a = ka*32 + 16*(j>>2) + 4g + (j&3) ----
        bf16x8 pa[2];
        #pragma unroll
        for (int ka = 0; ka < 2; ++ka)
        #pragma unroll
        for (int j = 0; j < 8; ++j)
            pa[ka][j] = (bf16_t)st[2 * ka + (j >> 2)][j & 3];

        // ---- PV ----
        __builtin_amdgcn_s_setprio(1);
        #pragma unroll
        for (int ka = 0; ka < 2; ++ka)
        #pragma unroll
        for (int fd = 0; fd < 4; ++fd) {
            const int row = fd * 16 + q;
            const int base = row * 64 + (g & 1) * 4;
            bf16x4 v0 = *(const bf16x4*)&sV[s][kb][base + (((ka * 4 +     (g >> 1)) ^ (row & 7)) * 8)];
            bf16x4 v1 = *(const bf16x4*)&sV[s][kb][base + (((ka * 4 + 2 + (g >> 1)) ^ (row & 7)) * 8)];
            bf16x8 bv;
            #pragma unroll
            for (int j = 0; j < 4; ++j) { bv[j] = v0[j]; bv[4 + j] = v1[j]; }
            oacc[fd] = mfma16(pa[ka], bv, oacc[fd]);
        }
        __builtin_amdgcn_s_setprio(0);

        __syncthreads();   // drains glds (issued a full compute-phase earlier)
    }

    // ---- parity combine (reuse sK region) + store ----
    float* cb = (float*)&sK[0][0][0];
    if (s == 1) {
        float* p = cb + (rg * 64 + l) * 20;
        p[0] = mrun; p[1] = lrun;
        #pragma unroll
        for (int fd = 0; fd < 4; ++fd) *(f32x4*)(p + 2 + fd * 4) = oacc[fd];
    }
    __syncthreads();
    if (s == 0) {
        const float* p = cb + (rg * 64 + l) * 20;
        const float mB = p[0], lB = p[1];
        const float mS = fmaxf(mrun, mB);
        const float aS = exp2f(mrun - mS), bS = exp2f(mB - mS);
        const float lS = lrun * aS + lB * bS;
        float aSo[4], bSo[4], inv[4];
        #pragma unroll
        for (int j = 0; j < 4; ++j) {
            aSo[j] = __shfl(aS, g * 4 + j, 64);
            bSo[j] = __shfl(bS, g * 4 + j, 64);
            inv[j] = 1.0f / __shfl(lS, g * 4 + j, 64);
        }
        #pragma unroll
        for (int fd = 0; fd < 4; ++fd) {
            f32x4 ob = *(const f32x4*)(p + 2 + fd * 4);
            #pragma unroll
            for (int j = 0; j < 4; ++j) {
                const float o = (oacc[fd][j] * aSo[j] + ob[j] * bSo[j]) * inv[j];
                Obuf[(size_t)(b * II + i0 + rg * 16 + g * 4 + j) * EE
                     + h * 64 + fd * 16 + q] = (bf16_t)o;
            }
        }
    }
}

extern "C" void kernel_launch(void* const* d_in, const int* in_sizes, int n_in,
                              void* d_out, int out_size, void* d_ws, size_t ws_size,
                              hipStream_t stream)
{
    const float* query  = (const float*)d_in[0];
    const float* key    = (const float*)d_in[1];
    const float* value  = (const float*)d_in[2];
    const float* dist   = (const float*)d_in[3];
    const float* in_w   = (const float*)d_in[4];
    const float* out_w  = (const float*)d_in[5];
    const float* mass_w = (const float*)d_in[6];
    float* out = (float*)d_out;

    char* ws = (char*)d_ws;
    bf16_t* Qp    = (bf16_t*)(ws);
    bf16_t* Kp    = (bf16_t*)(ws + 1 * 4194304);
    bf16_t* Vt    = (bf16_t*)(ws + 2 * 4194304);
    bf16_t* Obuf  = (bf16_t*)(ws + 3 * 4194304);
    float*  massT = (float*) (ws + 4 * 4194304);

    fused_pre<<<dim3(128, 4, 4), dim3(256), 0, stream>>>(
        query, key, value, in_w, mass_w, Qp, Kp, Vt, massT);
    attn_kernel<<<dim3(32, 4, 4), dim3(512), 0, stream>>>(Qp, Kp, Vt, massT, dist, Obuf);
    out_gemm<<<dim3(128, 4), dim3(256), 0, stream>>>(Obuf, out_w, out);
}

// Round 4
// 81.585 us; speedup vs baseline: 2.5623x; 1.1272x over previous
//
#include <hip/hip_runtime.h>
#include <hip/hip_bf16.h>
#include <math.h>

#define BB 4
#define II 2048
#define AA 2048
#define EE 256
#define HH 4

#define LOG2E 1.4426950408889634f
#define SCL   (0.125f * LOG2E)

typedef __bf16 bf16_t;
typedef bf16_t bf16x8 __attribute__((ext_vector_type(8)));
typedef bf16_t bf16x4 __attribute__((ext_vector_type(4)));
typedef float  f32x4  __attribute__((ext_vector_type(4)));

static __device__ __forceinline__ f32x4 mfma16(bf16x8 a, bf16x8 b, f32x4 c) {
    return __builtin_amdgcn_mfma_f32_16x16x32_bf16(a, b, c, 0, 0, 0);
}

static __device__ __forceinline__ void glds16(const bf16_t* g, const bf16_t* l) {
    __builtin_amdgcn_global_load_lds(
        (const __attribute__((address_space(1))) void*)g,
        (__attribute__((address_space(3))) void*)l, 16, 0, 0);
}

// ---------------- fused pre-pass: Q/K/V projections + mass ----------------
// C[m][n] = sum_k A[m][k]*B[n][k], scaled by cscale.
// TRANS==1: Vt tiled store with PV-matched column permutation.
static __device__ __forceinline__ void proj_body(
    const float* __restrict__ Aop, const float* __restrict__ Bop,
    bf16_t* __restrict__ Cout, int m0, int n0, int TRANS, float cscale,
    bf16_t (*sA)[72], bf16_t (*sB)[72])
{
    const int t = threadIdx.x;
    const int w = t >> 6, l = t & 63, g = l >> 4, q = l & 15;
    const int wm = w >> 1, wn = w & 1;
    const int r = t >> 2, s = t & 3;

    f32x4 acc[2][2] = {};

    for (int kt = 0; kt < 4; ++kt) {
        {
            const float* ga = Aop + (size_t)(m0 + r) * EE + kt * 64 + s * 16;
            float tmp[16];
            *(f32x4*)&tmp[0]  = *(const f32x4*)(ga + 0);
            *(f32x4*)&tmp[4]  = *(const f32x4*)(ga + 4);
            *(f32x4*)&tmp[8]  = *(const f32x4*)(ga + 8);
            *(f32x4*)&tmp[12] = *(const f32x4*)(ga + 12);
            bf16x8 w0, w1;
            #pragma unroll
            for (int i = 0; i < 8; ++i) { w0[i] = (bf16_t)tmp[i]; w1[i] = (bf16_t)tmp[8 + i]; }
            *(bf16x8*)&sA[r][s * 16]     = w0;
            *(bf16x8*)&sA[r][s * 16 + 8] = w1;
        }
        {
            const float* gb = Bop + (size_t)(n0 + r) * EE + kt * 64 + s * 16;
            float tmp[16];
            *(f32x4*)&tmp[0]  = *(const f32x4*)(gb + 0);
            *(f32x4*)&tmp[4]  = *(const f32x4*)(gb + 4);
            *(f32x4*)&tmp[8]  = *(const f32x4*)(gb + 8);
            *(f32x4*)&tmp[12] = *(const f32x4*)(gb + 12);
            bf16x8 w0, w1;
            #pragma unroll
            for (int i = 0; i < 8; ++i) { w0[i] = (bf16_t)tmp[i]; w1[i] = (bf16_t)tmp[8 + i]; }
            *(bf16x8*)&sB[r][s * 16]     = w0;
            *(bf16x8*)&sB[r][s * 16 + 8] = w1;
        }
        __syncthreads();
        #pragma unroll
        for (int ks = 0; ks < 2; ++ks) {
            bf16x8 aA[2], aB[2];
            #pragma unroll
            for (int f = 0; f < 2; ++f) {
                aA[f] = *(const bf16x8*)&sA[wm * 32 + f * 16 + q][ks * 32 + g * 8];
                aB[f] = *(const bf16x8*)&sB[wn * 32 + f * 16 + q][ks * 32 + g * 8];
            }
            #pragma unroll
            for (int fm = 0; fm < 2; ++fm)
            #pragma unroll
            for (int fn = 0; fn < 2; ++fn)
                acc[fm][fn] = mfma16(aA[fm], aB[fn], acc[fm][fn]);
        }
        __syncthreads();
    }
    #pragma unroll
    for (int fm = 0; fm < 2; ++fm)
    #pragma unroll
    for (int fn = 0; fn < 2; ++fn)
    #pragma unroll
    for (int j = 0; j < 4; ++j) {
        const int m = m0 + wm * 32 + fm * 16 + g * 4 + j;
        const int n = n0 + wn * 32 + fn * 16 + q;
        const bf16_t v = (bf16_t)(acc[fm][fn][j] * cscale);
        if (TRANS == 0) {
            Cout[(size_t)m * EE + n] = v;
        } else {
            const int bb = n >> 11, a = n & (AA - 1);
            const int a6 = a & 63;
            const int p6 = (a6 & 32) | ((a6 & 12) << 1) | ((a6 & 16) >> 2) | (a6 & 3);
            Cout[(size_t)bb * (AA * EE) + (size_t)(a >> 6) * (EE * 64) + m * 64 + p6] = v;
        }
    }
}

__global__ __launch_bounds__(256) void fused_pre(
    const float* __restrict__ query, const float* __restrict__ key,
    const float* __restrict__ value, const float* __restrict__ in_w,
    const float* __restrict__ mass_w,
    bf16_t* __restrict__ Qp, bf16_t* __restrict__ Kp, bf16_t* __restrict__ Vt,
    float* __restrict__ massT)
{
    __shared__ __align__(16) bf16_t sA[64][72];
    __shared__ __align__(16) bf16_t sB[64][72];
    const int z = blockIdx.z;
    if (z == 0) {
        proj_body(query, in_w, Qp, blockIdx.x * 64, blockIdx.y * 64, 0, SCL, sA, sB);
    } else if (z == 1) {
        proj_body(key, in_w + 65536, Kp, blockIdx.x * 64, blockIdx.y * 64, 0, 1.0f, sA, sB);
    } else if (z == 2) {
        proj_body(in_w + 131072, value, Vt, blockIdx.y * 64, blockIdx.x * 64, 1, 1.0f, sA, sB);
    } else {
        // mass: massT[b][h][a] = log_cosh(key[b,a,:].mass_w[h,:]) * LOG2E
        const int w = threadIdx.x >> 6, l = threadIdx.x & 63;
        const int p = blockIdx.y * 128 + blockIdx.x;      // 0..511
        const int row0 = p * 16 + w * 4;
        f32x4 mw[HH];
        #pragma unroll
        for (int hh = 0; hh < HH; ++hh)
            mw[hh] = *(const f32x4*)(mass_w + hh * EE + l * 4);
        #pragma unroll
        for (int rr = 0; rr < 4; ++rr) {
            const int row = row0 + rr;                     // b*AA + a
            f32x4 kv = *(const f32x4*)(key + (size_t)row * EE + l * 4);
            f32x4 sd;
            #pragma unroll
            for (int hh = 0; hh < HH; ++hh)
                sd[hh] = kv[0]*mw[hh][0] + kv[1]*mw[hh][1] + kv[2]*mw[hh][2] + kv[3]*mw[hh][3];
            #pragma unroll
            for (int off = 32; off >= 1; off >>= 1) {
                #pragma unroll
                for (int hh = 0; hh < HH; ++hh) sd[hh] += __shfl_xor(sd[hh], off, 64);
            }
            if (l == 0) {
                const int bb = row >> 11, a = row & (AA - 1);
                #pragma unroll
                for (int hh = 0; hh < HH; ++hh) {
                    float ax = fabsf(sd[hh]);
                    massT[((size_t)bb * HH + hh) * AA + a] =
                        (ax + log1pf(__expf(-2.0f * ax)) - 0.693147180559945f) * LOG2E;
                }
            }
        }
    }
}

// out[m][n] = sum_k Obuf[m][k] * W[n][k]
__global__ __launch_bounds__(256) void out_gemm(
    const bf16_t* __restrict__ Aop, const float* __restrict__ Bop,
    float* __restrict__ Cout)
{
    __shared__ __align__(16) bf16_t sA[64][72];
    __shared__ __align__(16) bf16_t sB[64][72];
    const int t = threadIdx.x;
    const int w = t >> 6, l = t & 63, g = l >> 4, q = l & 15;
    const int wm = w >> 1, wn = w & 1;
    const int m0 = blockIdx.x * 64, n0 = blockIdx.y * 64;
    const int r = t >> 2, s = t & 3;

    f32x4 acc[2][2] = {};

    for (int kt = 0; kt < 4; ++kt) {
        {
            const bf16_t* ga = Aop + (size_t)(m0 + r) * EE + kt * 64 + s * 16;
            *(bf16x8*)&sA[r][s * 16]     = *(const bf16x8*)(ga);
            *(bf16x8*)&sA[r][s * 16 + 8] = *(const bf16x8*)(ga + 8);
        }
        {
            const float* gb = Bop + (size_t)(n0 + r) * EE + kt * 64 + s * 16;
            float tmp[16];
            *(f32x4*)&tmp[0]  = *(const f32x4*)(gb + 0);
            *(f32x4*)&tmp[4]  = *(const f32x4*)(gb + 4);
            *(f32x4*)&tmp[8]  = *(const f32x4*)(gb + 8);
            *(f32x4*)&tmp[12] = *(const f32x4*)(gb + 12);
            bf16x8 w0, w1;
            #pragma unroll
            for (int i = 0; i < 8; ++i) { w0[i] = (bf16_t)tmp[i]; w1[i] = (bf16_t)tmp[8 + i]; }
            *(bf16x8*)&sB[r][s * 16]     = w0;
            *(bf16x8*)&sB[r][s * 16 + 8] = w1;
        }
        __syncthreads();
        #pragma unroll
        for (int ks = 0; ks < 2; ++ks) {
            bf16x8 aA[2], aB[2];
            #pragma unroll
            for (int f = 0; f < 2; ++f) {
                aA[f] = *(const bf16x8*)&sA[wm * 32 + f * 16 + q][ks * 32 + g * 8];
                aB[f] = *(const bf16x8*)&sB[wn * 32 + f * 16 + q][ks * 32 + g * 8];
            }
            #pragma unroll
            for (int fm = 0; fm < 2; ++fm)
            #pragma unroll
            for (int fn = 0; fn < 2; ++fn)
                acc[fm][fn] = mfma16(aA[fm], aB[fn], acc[fm][fn]);
        }
        __syncthreads();
    }
    #pragma unroll
    for (int fm = 0; fm < 2; ++fm)
    #pragma unroll
    for (int fn = 0; fn < 2; ++fn)
    #pragma unroll
    for (int j = 0; j < 4; ++j) {
        const int m = m0 + wm * 32 + fm * 16 + g * 4 + j;
        const int n = n0 + wn * 32 + fn * 16 + q;
        Cout[(size_t)m * EE + n] = acc[fm][fn][j];
    }
}

// ---------------- fused flash attention ----------------
// Grid (32,4,4) x 512 threads = 8 waves: parity s = wv>>2 (a-tiles 2k+s),
// row-group rg = wv&3 (16 i-rows). Per-parity double-buffered K/V LDS via
// global_load_lds (pre-swizzled source, linear dest). Softmax denominator
// accumulated as an extra ones-column MFMA (lacc, O-layout). Defer-max THR=8.
__global__ __launch_bounds__(512, 4) void attn_kernel(
    const bf16_t* __restrict__ Qp, const bf16_t* __restrict__ Kp,
    const bf16_t* __restrict__ Vt, const float* __restrict__ massT,
    const float* __restrict__ dist, bf16_t* __restrict__ Obuf)
{
    __shared__ __align__(16) bf16_t sK[2][2][4096];   // [parity][buf][64a x 64d] chunk^=(row&7)
    __shared__ __align__(16) bf16_t sV[2][2][4096];   // [parity][buf][64d x 64a'] chunk^=(row&7)
    __shared__ __align__(16) float  sM[2048];         // mass row (log2 domain)

    const int t = threadIdx.x;
    const int wv = t >> 6, l = t & 63, g = l >> 4, q = l & 15;
    const int s = wv >> 2, rg = wv & 3;
    const int h = blockIdx.y, b = blockIdx.z;
    const int i0 = blockIdx.x * 64;

    *(f32x4*)&sM[t * 4] = *(const f32x4*)(massT + ((size_t)b * HH + h) * AA + t * 4);

    // Q fragments (pre-scaled by SCL at projection)
    bf16x8 qf[2];
    #pragma unroll
    for (int ks = 0; ks < 2; ++ks)
        qf[ks] = *(const bf16x8*)(Qp + (size_t)(b * II + i0 + rg * 16 + q) * EE
                                     + h * 64 + ks * 32 + g * 8);

    // staging geometry: wave rg writes rows [rg*16, rg*16+16), lane covers (row, chunk)
    const int u0 = rg * 2;
    const int drow0 = u0 * 8 + (l >> 3);
    const int cs = (l & 7) ^ (drow0 & 7);   // constant pre-swizzled source chunk

    // incremental global pointers (parity stream starts at a0 = s*64)
    const bf16_t* pkg = Kp + ((size_t)b * AA + s * 64 + drow0) * EE + h * 64 + cs * 8;
    const bf16_t* pvg = Vt + (size_t)b * (AA * EE) + (size_t)s * (EE * 64)
                           + (size_t)(h * 64 + drow0) * 64 + cs * 8;
    const float*  pdg = dist + ((size_t)b * II + i0 + rg * 16 + q) * AA + s * 64 + g * 4;

    auto stage = [&](int kb) {
        #pragma unroll
        for (int u = 0; u < 2; ++u) {
            glds16(pkg + u * (8 * EE), &sK[s][kb][(u0 + u) * 512]);
            glds16(pvg + u * (8 * 64), &sV[s][kb][(u0 + u) * 512]);
        }
    };

    f32x4 rd[4];
    auto load_dist = [&]() {
        #pragma unroll
        for (int fa = 0; fa < 4; ++fa) rd[fa] = *(const f32x4*)(pdg + fa * 16);
    };

    stage(0);
    pkg += 128 * EE; pvg += 2 * (EE * 64);
    load_dist();
    pdg += 128;
    __syncthreads();

    float mrun = -INFINITY;
    f32x4 oacc[4] = {};
    f32x4 lacc = {};
    bf16x8 vone;
    #pragma unroll
    for (int j = 0; j < 8; ++j) vone[j] = (bf16_t)1.0f;

    int ma = s * 64;    // sM element offset for this tile

    #pragma unroll 2
    for (int k = 0; k < 16; ++k) {
        const int kb = k & 1;
        if (k < 15) {
            stage(kb ^ 1);
            pkg += 128 * EE; pvg += 2 * (EE * 64);
        }

        // ---- QK^T: S^T[a = fa*16+4g+j][i = q] ----
        f32x4 st[4] = {};
        __builtin_amdgcn_s_setprio(1);
        #pragma unroll
        for (int fa = 0; fa < 4; ++fa) {
            const int row = fa * 16 + q;
            #pragma unroll
            for (int ks = 0; ks < 2; ++ks) {
                bf16x8 ak = *(const bf16x8*)&sK[s][kb][row * 64 + (((ks * 4 + g) ^ (row & 7)) * 8)];
                st[fa] = mfma16(ak, qf[ks], st[fa]);
            }
        }
        __builtin_amdgcn_s_setprio(0);

        // ---- bias (log2 domain, scale pre-folded) + row max ----
        float mloc = -INFINITY;
        #pragma unroll
        for (int fa = 0; fa < 4; ++fa) {
            f32x4 ms = *(const f32x4*)&sM[ma + fa * 16 + g * 4];
            #pragma unroll
            for (int j = 0; j < 4; ++j) {
                float sv = fmaf(-ms[j], rd[fa][j], st[fa][j]);
                st[fa][j] = sv;
                mloc = fmaxf(mloc, sv);
            }
        }
        ma += 128;
        if (k < 15) { load_dist(); pdg += 128; }

        mloc = fmaxf(mloc, __shfl_xor(mloc, 16, 64));
        mloc = fmaxf(mloc, __shfl_xor(mloc, 32, 64));
        const bool skip = __all(mloc <= mrun + 8.0f);   // defer-max THR=8 (log2)
        float mnew = mrun;
        if (!skip) {
            mnew = fmaxf(mrun, mloc);
            const float sc = exp2f(mrun - mnew);
            mrun = mnew;
            float osc[4];
            #pragma unroll
            for (int j = 0; j < 4; ++j) osc[j] = __shfl(sc, g * 4 + j, 64);
            #pragma unroll
            for (int fd = 0; fd < 4; ++fd)
            #pragma unroll
            for (int j = 0; j < 4; ++j) oacc[fd][j] *= osc[j];
            #pragma unroll
            for (int j = 0; j < 4; ++j) lacc[j] *= osc[j];
        }

        // ---- P = exp2(S - m) ----
        #pragma unroll
        for (int fa = 0; fa < 4; ++fa)
        #pragma unroll
        for (int j = 0; j < 4; ++j)
            st[fa][j] = exp2f(st[fa][j] - mnew);

        // ---- pack P: slot (g,j) -> a = ka*32 + 16*(j>>2) + 4g + (j&3) ----
        bf16x8 pa[2];
        #pragma unroll
        for (int ka = 0; ka < 2; ++ka)
        #pragma unroll
        for (int j = 0; j < 8; ++j)
            pa[ka][j] = (bf16_t)st[2 * ka + (j >> 2)][j & 3];

        // ---- PV + ones-column denominator ----
        __builtin_amdgcn_s_setprio(1);
        #pragma unroll
        for (int ka = 0; ka < 2; ++ka) {
            #pragma unroll
            for (int fd = 0; fd < 4; ++fd) {
                const int row = fd * 16 + q;
                bf16x8 bv = *(const bf16x8*)&sV[s][kb][row * 64 + (((ka * 4 + g) ^ (row & 7)) * 8)];
                oacc[fd] = mfma16(pa[ka], bv, oacc[fd]);
            }
            lacc = mfma16(pa[ka], vone, lacc);
        }
        __builtin_amdgcn_s_setprio(0);

        __syncthreads();
    }

    // ---- parity combine (reuse sK region) + store ----
    // slot: 24 floats: [0]=mrun, [4..7]=lacc, [8..23]=oacc
    float* cb = (float*)&sK[0][0][0];
    if (s == 1) {
        float* p = cb + (rg * 64 + l) * 24;
        p[0] = mrun;
        *(f32x4*)(p + 4) = lacc;
        #pragma unroll
        for (int fd = 0; fd < 4; ++fd) *(f32x4*)(p + 8 + fd * 4) = oacc[fd];
    }
    __syncthreads();
    if (s == 0) {
        const float* p = cb + (rg * 64 + l) * 24;
        const float mB = p[0];
        const f32x4 lB = *(const f32x4*)(p + 4);
        const float mS = fmaxf(mrun, mB);
        const float aS = exp2f(mrun - mS), bS = exp2f(mB - mS);
        float aSo[4], bSo[4], inv[4];
        #pragma unroll
        for (int j = 0; j < 4; ++j) {
            aSo[j] = __shfl(aS, g * 4 + j, 64);
            bSo[j] = __shfl(bS, g * 4 + j, 64);
        }
        #pragma unroll
        for (int j = 0; j < 4; ++j)
            inv[j] = 1.0f / (lacc[j] * aSo[j] + lB[j] * bSo[j]);
        #pragma unroll
        for (int fd = 0; fd < 4; ++fd) {
            f32x4 ob = *(const f32x4*)(p + 8 + fd * 4);
            #pragma unroll
            for (int j = 0; j < 4; ++j) {
                const float o = (oacc[fd][j] * aSo[j] + ob[j] * bSo[j]) * inv[j];
                Obuf[(size_t)(b * II + i0 + rg * 16 + g * 4 + j) * EE
                     + h * 64 + fd * 16 + q] = (bf16_t)o;
            }
        }
    }
}

extern "C" void kernel_launch(void* const* d_in, const int* in_sizes, int n_in,
                              void* d_out, int out_size, void* d_ws, size_t ws_size,
                              hipStream_t stream)
{
    const float* query  = (const float*)d_in[0];
    const float* key    = (const float*)d_in[1];
    const float* value  = (const float*)d_in[2];
    const float* dist   = (const float*)d_in[3];
    const float* in_w   = (const float*)d_in[4];
    const float* out_w  = (const float*)d_in[5];
    const float* mass_w = (const float*)d_in[6];
    float* out = (float*)d_out;

    char* ws = (char*)d_ws;
    bf16_t* Qp    = (bf16_t*)(ws);
    bf16_t* Kp    = (bf16_t*)(ws + 1 * 4194304);
    bf16_t* Vt    = (bf16_t*)(ws + 2 * 4194304);
    bf16_t* Obuf  = (bf16_t*)(ws + 3 * 4194304);
    float*  massT = (float*) (ws + 4 * 4194304);

    fused_pre<<<dim3(128, 4, 4), dim3(256), 0, stream>>>(
        query, key, value, in_w, mass_w, Qp, Kp, Vt, massT);
    attn_kernel<<<dim3(32, 4, 4), dim3(512), 0, stream>>>(Qp, Kp, Vt, massT, dist, Obuf);
    out_gemm<<<dim3(128, 4), dim3(256), 0, stream>>>(Obuf, out_w, out);
}